// Round 8
// baseline (338.270 us; speedup 1.0000x reference)
//
#include <hip/hip_runtime.h>
#include <hip/hip_bf16.h>
#include <stdint.h>

typedef unsigned short u16;
typedef __bf16 bf16_t;
typedef bf16_t bf16x8 __attribute__((ext_vector_type(8)));
typedef short s16x4 __attribute__((ext_vector_type(4)));
typedef float f32x4 __attribute__((ext_vector_type(4)));
typedef float f32x16 __attribute__((ext_vector_type(16)));

__device__ __forceinline__ u16 f2bf(float f) {
    union { float f; uint32_t i; } v; v.f = f;
    uint32_t i = v.i;
    uint32_t r = (i + 0x7FFFu + ((i >> 16) & 1u)) >> 16;   // RNE
    return (u16)r;
}

// async global->LDS, 16B per lane; LDS dest = wave-uniform base + lane*16
__device__ __forceinline__ void gload_lds16(const u16* g, u16* l) {
    auto gp = (const __attribute__((address_space(1))) void*)g;
    auto lp = (__attribute__((address_space(3))) void*)(uintptr_t)l;
    __builtin_amdgcn_global_load_lds(gp, lp, 16, 0, 0);
}

// ---------------------------------------------------------------------------
// fp32 -> bf16 bulk convert (x activations). n4 = count of float4 groups.
// ---------------------------------------------------------------------------
__global__ void convert_f32_bf16_kernel(const float* __restrict__ src,
                                        u16* __restrict__ dst, int n4) {
    int i = blockIdx.x * blockDim.x + threadIdx.x;
    if (i < n4) {
        float4 v = ((const float4*)src)[i];
        ushort4 o;
        o.x = f2bf(v.x); o.y = f2bf(v.y); o.z = f2bf(v.z); o.w = f2bf(v.w);
        ((ushort4*)dst)[i] = o;
    }
}

// ---------------------------------------------------------------------------
// Inverted (coalesced-read) W_qk transpose: one block per input row k.
// W_qk [768][1536] col c = h*128 + dd*2 + qk -> Wqkt row r = qk*768 + h*64 + dd.
// Q rows (r<768) pre-scaled by 1/sqrt(64)=0.125 (exact in bf16).
// ---------------------------------------------------------------------------
__global__ void transpose_qk_kernel(const float* __restrict__ W, const float* __restrict__ b,
                                    u16* __restrict__ Wt, float* __restrict__ bp) {
    int k = blockIdx.x;                 // 0..767 input row
    const float* row = W + (size_t)k * 1536;
    for (int c = threadIdx.x; c < 1536; c += 256) {
        int qk = c & 1;
        int r  = qk * 768 + (c >> 7) * 64 + ((c >> 1) & 63);
        float s = qk ? 1.0f : 0.125f;
        Wt[(size_t)r * 768 + k] = f2bf(s * row[c]);
    }
    if (k == 0) {
        for (int c = threadIdx.x; c < 1536; c += 256) {
            int qk = c & 1;
            int r  = qk * 768 + (c >> 7) * 64 + ((c >> 1) & 63);
            bp[r] = (qk ? 1.0f : 0.125f) * b[c];
        }
    }
}

// fused square 768x768 transposes (coalesced read): blocks 0..767 -> Wv,
// blocks 768..1535 -> Wproj. Wt[n][k] = bf16(W[k][n]).
__global__ void transpose_sq2_kernel(const float* __restrict__ Wv, u16* __restrict__ Wvt,
                                     const float* __restrict__ Wp, u16* __restrict__ Wpt) {
    int id = blockIdx.x;
    const float* W = (id < 768) ? Wv : Wp;
    u16* Wt        = (id < 768) ? Wvt : Wpt;
    int k = (id < 768) ? id : (id - 768);   // input row
    const float* row = W + (size_t)k * 768;
    for (int n = threadIdx.x; n < 768; n += 256)
        Wt[(size_t)n * 768 + k] = f2bf(row[n]);
}

// ---------------------------------------------------------------------------
// Fused QK+V projection GEMM, 2-phase dbuf staging, 32x32x16 MFMA fragments
// (2x FLOP per LDS byte vs 16x16x32 -- the R7 counters showed LDS-read-BW
// bound: 16 ds_read_b128/wave/K-step for 32 MFMAs = 128KB/CU/K-step vs
// 128B/cy peak). Wave tile stays 64x64 = 2x2 of 32x32 frags.
// 32x32x16 layouts: A/B lane l: row/col = l&31, k = (l>>5)*8 + e.
// C/D lane l: col = l&31, row = (reg&3) + 8*(reg>>2) + 4*(l>>5).
// 2304 blocks = 128 m-tiles x 18 n-tiles (0..11 QK swapped, 12..17 V).
// ---------------------------------------------------------------------------
__global__ __launch_bounds__(256)
void gemm_qkv_kernel(const u16* __restrict__ A,
                     const u16* __restrict__ Wqkt, const u16* __restrict__ Wvt,
                     const float* __restrict__ bqkp, const float* __restrict__ bv,
                     u16* __restrict__ Qp, u16* __restrict__ Kp, u16* __restrict__ Vp) {
    __shared__ __attribute__((aligned(16))) u16 As[2][128 * 64];
    __shared__ __attribute__((aligned(16))) u16 Bs[2][128 * 64];
    const int K = 768;

    const int tid  = threadIdx.x;
    const int lane = tid & 63;
    const int wave = tid >> 6;
    const int l32  = lane & 31;
    const int hi   = lane >> 5;          // 0/1
    const int s7   = lane & 7;           // (row&7) for frag rows (32-mult offsets)
    const int cpx  = 2304 >> 3;
    const int swz  = ((int)blockIdx.x & 7) * cpx + ((int)blockIdx.x >> 3);
    const int mt   = swz / 18;
    const int nt   = swz % 18;
    const bool vmode = nt >= 12;
    const int m0 = mt * 128;
    const int n0 = (vmode ? nt - 12 : nt) * 128;
    const u16* Bt = vmode ? Wvt : Wqkt;
    const float* bias = vmode ? bv : bqkp;
    const int wm = (wave & 1) * 64;
    const int wn = (wave >> 1) * 64;

    f32x16 acc[2][2] = {};               // [first-op frag][second-op frag]

    const int rs   = lane >> 3;          // staging row-in-8
    const int gseg = (lane & 7) ^ rs;
    const u16* Ag[4]; const u16* Bg[4];
#pragma unroll
    for (int c = 0; c < 4; c++) {
        Ag[c] = A  + (size_t)(m0 + c * 32 + wave * 8 + rs) * K + gseg * 8;
        Bg[c] = Bt + (size_t)(n0 + c * 32 + wave * 8 + rs) * K + gseg * 8;
    }

    // prologue: stage K-step 0 into buffer 0
#pragma unroll
    for (int c = 0; c < 4; c++) {
        gload_lds16(Ag[c], &As[0][wave * 512 + c * 2048]);
        gload_lds16(Bg[c], &Bs[0][wave * 512 + c * 2048]);
    }

    int cur = 0;
    for (int t = 0; t < 12; ++t) {
        __syncthreads();                 // buf[cur] staged (barrier drains vmcnt)
        if (t < 11) {
#pragma unroll
            for (int c = 0; c < 4; c++) {
                gload_lds16(Ag[c] + (t + 1) * 64, &As[cur ^ 1][wave * 512 + c * 2048]);
                gload_lds16(Bg[c] + (t + 1) * 64, &Bs[cur ^ 1][wave * 512 + c * 2048]);
            }
        }
        const u16* Asc = As[cur];
        const u16* Bsc = Bs[cur];

        // frag reads: af[fi][kb] = A rows wm+fi*32+l32, k-slice kb*16 + hi*8
        bf16x8 af[2][4], bfr[2][4];
#pragma unroll
        for (int fi = 0; fi < 2; fi++) {
            int ra = (wm + fi * 32 + l32) * 64;
            int rb = (wn + fi * 32 + l32) * 64;
#pragma unroll
            for (int kb = 0; kb < 4; kb++) {
                int seg = ((2 * kb + hi) ^ s7) * 8;
                af[fi][kb]  = *(const bf16x8*)&Asc[ra + seg];
                bfr[fi][kb] = *(const bf16x8*)&Bsc[rb + seg];
            }
        }
        __builtin_amdgcn_s_setprio(1);
        if (vmode) {
            // unswapped: D rows = tokens (A), cols = features (B)
#pragma unroll
            for (int fa = 0; fa < 2; fa++)
#pragma unroll
                for (int fb = 0; fb < 2; fb++)
#pragma unroll
                    for (int kb = 0; kb < 4; kb++)
                        acc[fa][fb] = __builtin_amdgcn_mfma_f32_32x32x16_bf16(
                            af[fa][kb], bfr[fb][kb], acc[fa][fb], 0, 0, 0);
        } else {
            // swapped: D rows = features (B), cols = tokens (A)
#pragma unroll
            for (int fb = 0; fb < 2; fb++)
#pragma unroll
                for (int fa = 0; fa < 2; fa++)
#pragma unroll
                    for (int kb = 0; kb < 4; kb++)
                        acc[fb][fa] = __builtin_amdgcn_mfma_f32_32x32x16_bf16(
                            bfr[fb][kb], af[fa][kb], acc[fb][fa], 0, 0, 0);
        }
        __builtin_amdgcn_s_setprio(0);
        cur ^= 1;
    }

    if (vmode) {
        // D row = token (reg&3)+8*(reg>>2)+4*hi, col = dv feature l32.
#pragma unroll
        for (int p = 0; p < 2; p++) {          // fa: token frag
#pragma unroll
            for (int q = 0; q < 2; q++) {      // fb: feature frag
                int cnb = n0 + wn + q * 32;
                int h   = cnb >> 6;
                int dv  = (cnb & 63) + l32;
                float bvv = bias[cnb + l32];
#pragma unroll
                for (int rg = 0; rg < 4; rg++) {
                    int tok0 = m0 + wm + p * 32 + rg * 8 + 4 * hi;
                    int bb = tok0 >> 10, n = tok0 & 1023;
                    ushort4 o;
                    o.x = f2bf(acc[p][q][4 * rg + 0] + bvv);
                    o.y = f2bf(acc[p][q][4 * rg + 1] + bvv);
                    o.z = f2bf(acc[p][q][4 * rg + 2] + bvv);
                    o.w = f2bf(acc[p][q][4 * rg + 3] + bvv);
                    *(ushort4*)&Vp[((size_t)((bb * 12 + h) * 64 + dv)) * 1024 + n] = o;
                }
            }
        }
    } else {
        // D row = feature (reg&3)+8*(reg>>2)+4*hi, col = token l32.
#pragma unroll
        for (int p = 0; p < 2; p++) {          // fb: feature frag
#pragma unroll
            for (int q = 0; q < 2; q++) {      // fa: token frag
                int tok = m0 + wm + q * 32 + l32;
                int bb = tok >> 10, n = tok & 1023;
#pragma unroll
                for (int rg = 0; rg < 4; rg++) {
                    int f0g = n0 + wn + p * 32 + rg * 8 + 4 * hi;
                    float4 bv4 = *(const float4*)&bias[f0g];
                    int qk = f0g >= 768;
                    int hd = f0g - qk * 768;
                    int h  = hd >> 6;
                    int d0 = hd & 63;
                    u16* dst = qk ? Kp : Qp;
                    ushort4 o;
                    o.x = f2bf(acc[p][q][4 * rg + 0] + bv4.x);
                    o.y = f2bf(acc[p][q][4 * rg + 1] + bv4.y);
                    o.z = f2bf(acc[p][q][4 * rg + 2] + bv4.z);
                    o.w = f2bf(acc[p][q][4 * rg + 3] + bv4.w);
                    *(ushort4*)&dst[((size_t)((bb * 12 + h) * 1024 + n)) * 64 + d0] = o;
                }
            }
        }
    }
}

// ---------------------------------------------------------------------------
// Out-projection GEMM (fp32 out, SWAPPED), 2-phase dbuf, 32x32x16 MFMA.
// ---------------------------------------------------------------------------
__global__ __launch_bounds__(256)
void gemm_out_kernel(const u16* __restrict__ A, const u16* __restrict__ Bt,
                     const float* __restrict__ bias, float* __restrict__ Cout,
                     int M, int N, int K) {
    __shared__ __attribute__((aligned(16))) u16 As[2][128 * 64];
    __shared__ __attribute__((aligned(16))) u16 Bs[2][128 * 64];

    const int tid  = threadIdx.x;
    const int lane = tid & 63;
    const int wave = tid >> 6;
    const int l32  = lane & 31;
    const int hi   = lane >> 5;
    const int s7   = lane & 7;
    const int nxt = N >> 7;
    const int cpx = (int)gridDim.x >> 3;
    const int swz = ((int)blockIdx.x & 7) * cpx + ((int)blockIdx.x >> 3);
    const int m0 = (swz / nxt) * 128;
    const int n0 = (swz % nxt) * 128;
    const int wm = (wave & 1) * 64;
    const int wn = (wave >> 1) * 64;

    f32x16 acc[2][2] = {};

    const int rs   = lane >> 3;
    const int gseg = (lane & 7) ^ rs;
    const u16* Ag[4]; const u16* Bg[4];
#pragma unroll
    for (int c = 0; c < 4; c++) {
        Ag[c] = A  + (size_t)(m0 + c * 32 + wave * 8 + rs) * K + gseg * 8;
        Bg[c] = Bt + (size_t)(n0 + c * 32 + wave * 8 + rs) * K + gseg * 8;
    }
    const int nk = K >> 6;

    // prologue
#pragma unroll
    for (int c = 0; c < 4; c++) {
        gload_lds16(Ag[c], &As[0][wave * 512 + c * 2048]);
        gload_lds16(Bg[c], &Bs[0][wave * 512 + c * 2048]);
    }

    int cur = 0;
    for (int t = 0; t < nk; ++t) {
        __syncthreads();
        if (t < nk - 1) {
#pragma unroll
            for (int c = 0; c < 4; c++) {
                gload_lds16(Ag[c] + (t + 1) * 64, &As[cur ^ 1][wave * 512 + c * 2048]);
                gload_lds16(Bg[c] + (t + 1) * 64, &Bs[cur ^ 1][wave * 512 + c * 2048]);
            }
        }
        const u16* Asc = As[cur];
        const u16* Bsc = Bs[cur];

        bf16x8 af[2][4], bfr[2][4];
#pragma unroll
        for (int fi = 0; fi < 2; fi++) {
            int ra = (wm + fi * 32 + l32) * 64;
            int rb = (wn + fi * 32 + l32) * 64;
#pragma unroll
            for (int kb = 0; kb < 4; kb++) {
                int seg = ((2 * kb + hi) ^ s7) * 8;
                af[fi][kb]  = *(const bf16x8*)&Asc[ra + seg];
                bfr[fi][kb] = *(const bf16x8*)&Bsc[rb + seg];
            }
        }
        __builtin_amdgcn_s_setprio(1);
#pragma unroll
        for (int fb = 0; fb < 2; fb++)
#pragma unroll
            for (int fa = 0; fa < 2; fa++)
#pragma unroll
                for (int kb = 0; kb < 4; kb++)
                    acc[fb][fa] = __builtin_amdgcn_mfma_f32_32x32x16_bf16(
                        bfr[fb][kb], af[fa][kb], acc[fb][fa], 0, 0, 0);
        __builtin_amdgcn_s_setprio(0);
        cur ^= 1;
    }

#pragma unroll
    for (int p = 0; p < 2; p++) {              // feature frag
#pragma unroll
        for (int q = 0; q < 2; q++) {          // token frag
            int tok = m0 + wm + q * 32 + l32;
#pragma unroll
            for (int rg = 0; rg < 4; rg++) {
                int f0g = n0 + wn + p * 32 + rg * 8 + 4 * hi;
                float4 bv = *(const float4*)&bias[f0g];
                float4 o;
                o.x = acc[p][q][4 * rg + 0] + bv.x;
                o.y = acc[p][q][4 * rg + 1] + bv.y;
                o.z = acc[p][q][4 * rg + 2] + bv.z;
                o.w = acc[p][q][4 * rg + 3] + bv.w;
                *(float4*)&Cout[(size_t)tok * N + f0g] = o;
            }
        }
    }
}

// ---------------------------------------------------------------------------
// MFMA flash attention v6b (R4 form, frozen): 512-thread blocks, grid 768
// (XCD-chunked). Wave owns 32 q-rows. Dbuf K/V staging, setprio on MFMA.
// ---------------------------------------------------------------------------
__global__ __launch_bounds__(512)
void attention_mfma_kernel(const u16* __restrict__ Qp, const u16* __restrict__ Kp,
                           const u16* __restrict__ Vp, u16* __restrict__ attout) {
    __shared__ __attribute__((aligned(16))) u16 Ks[2][64 * 64];   // [key][d], swizzled
    __shared__ __attribute__((aligned(16))) u16 Vs[2][64 * 64];   // [dv][key], swizzled

    const int tid  = threadIdx.x;
    const int wave = tid >> 6;          // 0..7
    const int lane = tid & 63;
    const int l16  = lane & 15;
    const int quad = lane >> 4;
    const int flat = blockIdx.x;
    const int swz  = (flat & 7) * 96 + (flat >> 3);
    const int bh   = swz >> 2;          // 0..191 == head
    const int b    = bh / 12, h = bh % 12;
    const int q0   = (swz & 3) * 256 + wave * 32;

    const u16* Qhead = Qp + (size_t)bh * 1024 * 64;
    const u16* Khead = Kp + (size_t)bh * 1024 * 64;
    const u16* Vhead = Vp + (size_t)bh * 64 * 1024;

    bf16x8 qf[2][2];
#pragma unroll
    for (int qb = 0; qb < 2; qb++) {
        const u16* qrow = Qhead + (size_t)(q0 + qb * 16 + l16) * 64;
        qf[qb][0] = *(const bf16x8*)(qrow + quad * 8);
        qf[qb][1] = *(const bf16x8*)(qrow + 32 + quad * 8);
    }

    f32x4 oacc[2][4];
#pragma unroll
    for (int qb = 0; qb < 2; qb++)
#pragma unroll
        for (int db = 0; db < 4; db++) oacc[qb][db] = (f32x4){0.f, 0.f, 0.f, 0.f};
    float l_part[2] = {0.f, 0.f};

    const int srow = tid >> 3;                  // 0..63
    const int gseg = (tid & 7) ^ (srow & 7);
    const u16* Kg = Khead + (size_t)srow * 64 + gseg * 8;    // + t*4096 per tile
    const u16* Vg = Vhead + (size_t)srow * 1024 + gseg * 8;  // + t*64 per tile
    const int sw7 = l16 & 7;

    gload_lds16(Kg, &Ks[0][wave * 512]);
    gload_lds16(Vg, &Vs[0][wave * 512]);

    int cur = 0;
    for (int t = 0; t < 16; ++t) {
        __syncthreads();
        if (t < 15) {
            gload_lds16(Kg + (t + 1) * 4096, &Ks[cur ^ 1][wave * 512]);
            gload_lds16(Vg + (t + 1) * 64,   &Vs[cur ^ 1][wave * 512]);
        }
        const u16* Ksc = Ks[cur];
        const u16* Vsc = Vs[cur];

        union { uint32_t u[4]; bf16x8 v; } pf8[2][2];   // [qb][jp]
        {
            bf16x8 kf[4][2];
#pragma unroll
            for (int jb = 0; jb < 4; jb++) {
#pragma unroll
                for (int hf = 0; hf < 2; hf++)
                    kf[jb][hf] = *(const bf16x8*)&Ksc[(jb * 16 + l16) * 64 +
                                                      (((hf * 4 + quad) ^ sw7) * 8)];
            }
#pragma unroll
            for (int qb = 0; qb < 2; qb++) {
#pragma unroll
                for (int jb = 0; jb < 4; jb++) {
                    f32x4 st = (f32x4){0.f, 0.f, 0.f, 0.f};
                    __builtin_amdgcn_s_setprio(1);
                    st = __builtin_amdgcn_mfma_f32_16x16x32_bf16(kf[jb][0], qf[qb][0], st, 0, 0, 0);
                    st = __builtin_amdgcn_mfma_f32_16x16x32_bf16(kf[jb][1], qf[qb][1], st, 0, 0, 0);
                    __builtin_amdgcn_s_setprio(0);
                    float e0 = __expf(st[0]), e1 = __expf(st[1]);
                    float e2 = __expf(st[2]), e3 = __expf(st[3]);
                    l_part[qb] += (e0 + e1) + (e2 + e3);
                    union { __hip_bfloat162 h2; uint32_t u; } c0, c1;
                    c0.h2 = __float22bfloat162_rn(make_float2(e0, e1));
                    c1.h2 = __float22bfloat162_rn(make_float2(e2, e3));
                    pf8[qb][jb >> 1].u[(jb & 1) * 2 + 0] = c0.u;
                    pf8[qb][jb >> 1].u[(jb & 1) * 2 + 1] = c1.u;
                }
            }
        }

        __builtin_amdgcn_s_setprio(1);
#pragma unroll
        for (int db = 0; db < 4; db++) {
#pragma unroll
            for (int jp = 0; jp < 2; jp++) {
                union { s16x4 hh[2]; bf16x8 v; } vb8;
                int glo = 4 * jp + (quad >> 1);
                int ghi = glo + 2;
                vb8.hh[0] = *(const s16x4*)&Vsc[(db * 16 + l16) * 64 +
                                                ((glo ^ sw7) * 8) + (quad & 1) * 4];
                vb8.hh[1] = *(const s16x4*)&Vsc[(db * 16 + l16) * 64 +
                                                ((ghi ^ sw7) * 8) + (quad & 1) * 4];
#pragma unroll
                for (int qb = 0; qb < 2; qb++)
                    oacc[qb][db] = __builtin_amdgcn_mfma_f32_16x16x32_bf16(
                        pf8[qb][jp].v, vb8.v, oacc[qb][db], 0, 0, 0);
            }
        }
        __builtin_amdgcn_s_setprio(0);
        cur ^= 1;
    }

#pragma unroll
    for (int qb = 0; qb < 2; qb++) {
        float l = l_part[qb];
        l += __shfl_xor(l, 16);
        l += __shfl_xor(l, 32);
        float linv[4];
#pragma unroll
        for (int r = 0; r < 4; r++)
            linv[r] = 1.0f / __shfl(l, quad * 4 + r);
        u16* orow = attout + (size_t)(b * 1024 + q0 + qb * 16 + quad * 4) * 768 + h * 64 + l16;
#pragma unroll
        for (int db = 0; db < 4; db++)
#pragma unroll
            for (int r = 0; r < 4; r++)
                orow[(size_t)r * 768 + db * 16] = f2bf(oacc[qb][db][r] * linv[r]);
    }
}

// ---------------------------------------------------------------------------
extern "C" void kernel_launch(void* const* d_in, const int* in_sizes, int n_in,
                              void* d_out, int out_size, void* d_ws, size_t ws_size,
                              hipStream_t stream) {
    const float* x      = (const float*)d_in[0];
    const float* W_qk   = (const float*)d_in[1];
    const float* b_qk   = (const float*)d_in[2];
    const float* W_v    = (const float*)d_in[3];
    const float* b_v    = (const float*)d_in[4];
    const float* W_proj = (const float*)d_in[5];
    const float* b_proj = (const float*)d_in[6];
    float* out = (float*)d_out;

    char* ws = (char*)d_ws;
    size_t off = 0;
    auto alloc = [&](size_t bytes) { void* p = ws + off; off += (bytes + 255) & ~255ull; return p; };
    u16*   xb     = (u16*)alloc((size_t)16384 * 768 * 2);
    u16*   Wqkt   = (u16*)alloc((size_t)1536 * 768 * 2);
    float* bqkp   = (float*)alloc(1536 * 4);
    u16*   Wvt    = (u16*)alloc((size_t)768 * 768 * 2);
    u16*   Wprojt = (u16*)alloc((size_t)768 * 768 * 2);
    u16*   Qp     = (u16*)alloc((size_t)16384 * 768 * 2);
    u16*   Kp     = (u16*)alloc((size_t)16384 * 768 * 2);
    u16*   Vp     = (u16*)alloc((size_t)16384 * 768 * 2);
    u16*   attout = (u16*)alloc((size_t)16384 * 768 * 2);

    convert_f32_bf16_kernel<<<12288, 256, 0, stream>>>(x, xb, 3145728);
    transpose_qk_kernel<<<768, 256, 0, stream>>>(W_qk, b_qk, Wqkt, bqkp);
    transpose_sq2_kernel<<<1536, 256, 0, stream>>>(W_v, Wvt, W_proj, Wprojt);

    // fused QK+V projection (Q pre-scaled by 0.125)
    gemm_qkv_kernel<<<2304, 256, 0, stream>>>(xb, Wqkt, Wvt, bqkp, b_v, Qp, Kp, Vp);
    // attention -> attout (bf16, [token][768])
    attention_mfma_kernel<<<768, 512, 0, stream>>>(Qp, Kp, Vp, attout);
    // output projection -> d_out (fp32)
    gemm_out_kernel<<<768, 256, 0, stream>>>(attout, Wprojt, b_proj, out, 16384, 768, 768);
}

// Round 9
// 313.476 us; speedup vs baseline: 1.0791x; 1.0791x over previous
//
#include <hip/hip_runtime.h>
#include <hip/hip_bf16.h>
#include <stdint.h>

typedef unsigned short u16;
typedef __bf16 bf16_t;
typedef bf16_t bf16x8 __attribute__((ext_vector_type(8)));
typedef short s16x4 __attribute__((ext_vector_type(4)));
typedef float f32x4 __attribute__((ext_vector_type(4)));

__device__ __forceinline__ u16 f2bf(float f) {
    union { float f; uint32_t i; } v; v.f = f;
    uint32_t i = v.i;
    uint32_t r = (i + 0x7FFFu + ((i >> 16) & 1u)) >> 16;   // RNE
    return (u16)r;
}

// async global->LDS, 16B per lane; LDS dest = wave-uniform base + lane*16
__device__ __forceinline__ void gload_lds16(const u16* g, u16* l) {
    auto gp = (const __attribute__((address_space(1))) void*)g;
    auto lp = (__attribute__((address_space(3))) void*)(uintptr_t)l;
    __builtin_amdgcn_global_load_lds(gp, lp, 16, 0, 0);
}

// ---------------------------------------------------------------------------
// Merged prep kernel (single dispatch, disjoint block ranges, bit-exact):
//  blocks 0..12287      : fp32->bf16 convert of x (float4 granules)
//  blocks 12288..13055  : W_qk transpose row k = id-12288 (coalesced read)
//  blocks 13056..14591  : square transposes (Wv then Wproj)
// ---------------------------------------------------------------------------
__global__ void prep_kernel(const float* __restrict__ x, u16* __restrict__ xb,
                            const float* __restrict__ Wqk, const float* __restrict__ bqk,
                            u16* __restrict__ Wqkt, float* __restrict__ bqkp,
                            const float* __restrict__ Wv, u16* __restrict__ Wvt,
                            const float* __restrict__ Wp, u16* __restrict__ Wpt) {
    int id = blockIdx.x;
    if (id < 12288) {
        int i = id * 256 + threadIdx.x;          // 12288*256 == 3145728 exactly
        float4 v = ((const float4*)x)[i];
        ushort4 o;
        o.x = f2bf(v.x); o.y = f2bf(v.y); o.z = f2bf(v.z); o.w = f2bf(v.w);
        ((ushort4*)xb)[i] = o;
    } else if (id < 13056) {
        int k = id - 12288;                      // 0..767 input row
        const float* row = Wqk + (size_t)k * 1536;
        for (int c = threadIdx.x; c < 1536; c += 256) {
            int qk = c & 1;
            int r  = qk * 768 + (c >> 7) * 64 + ((c >> 1) & 63);
            float s = qk ? 1.0f : 0.125f;
            Wqkt[(size_t)r * 768 + k] = f2bf(s * row[c]);
        }
        if (k == 0) {
            for (int c = threadIdx.x; c < 1536; c += 256) {
                int qk = c & 1;
                int r  = qk * 768 + (c >> 7) * 64 + ((c >> 1) & 63);
                bqkp[r] = (qk ? 1.0f : 0.125f) * bqk[c];
            }
        }
    } else {
        int sid = id - 13056;                    // 0..1535
        const float* W = (sid < 768) ? Wv : Wp;
        u16* Wt        = (sid < 768) ? Wvt : Wpt;
        int k = (sid < 768) ? sid : (sid - 768);
        const float* row = W + (size_t)k * 768;
        for (int n = threadIdx.x; n < 768; n += 256)
            Wt[(size_t)n * 768 + k] = f2bf(row[n]);
    }
}

// ---------------------------------------------------------------------------
// Fused QK+V projection GEMM, 2-phase double-buffered staging (T3):
// one barrier per K-step; tile t+1's global_load_lds issued before tile t's
// compute so HBM latency hides under LDS-read+MFMA. (R7 version, known-good.)
// 2304 blocks = 128 m-tiles x 18 n-tiles (0..11 QK swapped, 12..17 V).
// ---------------------------------------------------------------------------
__global__ __launch_bounds__(256)
void gemm_qkv_kernel(const u16* __restrict__ A,
                     const u16* __restrict__ Wqkt, const u16* __restrict__ Wvt,
                     const float* __restrict__ bqkp, const float* __restrict__ bv,
                     u16* __restrict__ Qp, u16* __restrict__ Kp, u16* __restrict__ Vp) {
    __shared__ __attribute__((aligned(16))) u16 As[2][128 * 64];
    __shared__ __attribute__((aligned(16))) u16 Bs[2][128 * 64];
    const int K = 768;

    const int tid  = threadIdx.x;
    const int lane = tid & 63;
    const int wave = tid >> 6;
    const int l16  = lane & 15;
    const int quad = lane >> 4;
    const int cpx  = 2304 >> 3;
    const int swz  = ((int)blockIdx.x & 7) * cpx + ((int)blockIdx.x >> 3);
    const int mt   = swz / 18;
    const int nt   = swz % 18;
    const bool vmode = nt >= 12;
    const int m0 = mt * 128;
    const int n0 = (vmode ? nt - 12 : nt) * 128;
    const u16* Bt = vmode ? Wvt : Wqkt;
    const float* bias = vmode ? bv : bqkp;
    const int wm = (wave & 1) * 64;
    const int wn = (wave >> 1) * 64;

    f32x4 acc[4][4];
#pragma unroll
    for (int i = 0; i < 4; i++)
#pragma unroll
        for (int j = 0; j < 4; j++) acc[i][j] = (f32x4){0.f, 0.f, 0.f, 0.f};

    const int rs   = lane >> 3;                 // 0..7
    const int gseg = (lane & 7) ^ rs;
    const u16* Ag[4]; const u16* Bg[4];
#pragma unroll
    for (int c = 0; c < 4; c++) {
        Ag[c] = A  + (size_t)(m0 + c * 32 + wave * 8 + rs) * K + gseg * 8;
        Bg[c] = Bt + (size_t)(n0 + c * 32 + wave * 8 + rs) * K + gseg * 8;
    }
    const int sw7 = l16 & 7;

    // prologue: stage K-step 0 into buffer 0
#pragma unroll
    for (int c = 0; c < 4; c++) {
        gload_lds16(Ag[c], &As[0][wave * 512 + c * 2048]);
        gload_lds16(Bg[c], &Bs[0][wave * 512 + c * 2048]);
    }

    int cur = 0;
    for (int t = 0; t < 12; ++t) {
        __syncthreads();                 // buf[cur] staged (barrier drains vmcnt)
        if (t < 11) {
#pragma unroll
            for (int c = 0; c < 4; c++) {
                gload_lds16(Ag[c] + (t + 1) * 64, &As[cur ^ 1][wave * 512 + c * 2048]);
                gload_lds16(Bg[c] + (t + 1) * 64, &Bs[cur ^ 1][wave * 512 + c * 2048]);
            }
        }
        const u16* Asc = As[cur];
        const u16* Bsc = Bs[cur];

        bf16x8 af[4][2], bfr[4][2];
#pragma unroll
        for (int i = 0; i < 4; i++) {
#pragma unroll
            for (int hh = 0; hh < 2; hh++) {
                af[i][hh]  = *(const bf16x8*)&Asc[(wm + i * 16 + l16) * 64 +
                                                  (((hh * 4 + quad) ^ sw7) * 8)];
                bfr[i][hh] = *(const bf16x8*)&Bsc[(wn + i * 16 + l16) * 64 +
                                                  (((hh * 4 + quad) ^ sw7) * 8)];
            }
        }
        __builtin_amdgcn_s_setprio(1);
        if (vmode) {
#pragma unroll
            for (int i = 0; i < 4; i++)
#pragma unroll
                for (int j = 0; j < 4; j++)
#pragma unroll
                    for (int hh = 0; hh < 2; hh++)
                        acc[i][j] = __builtin_amdgcn_mfma_f32_16x16x32_bf16(af[i][hh], bfr[j][hh], acc[i][j], 0, 0, 0);
        } else {
#pragma unroll
            for (int i = 0; i < 4; i++)
#pragma unroll
                for (int j = 0; j < 4; j++)
#pragma unroll
                    for (int hh = 0; hh < 2; hh++)
                        acc[i][j] = __builtin_amdgcn_mfma_f32_16x16x32_bf16(bfr[j][hh], af[i][hh], acc[i][j], 0, 0, 0);
        }
        __builtin_amdgcn_s_setprio(0);
        cur ^= 1;
    }

    if (vmode) {
        // D row = token quad*4+r, col = feature l16 per 16x16 tile.
#pragma unroll
        for (int j = 0; j < 4; j++) {
            int cnb = n0 + wn + j * 16;
            int h   = cnb >> 6;
            int dv  = (cnb & 63) + l16;
            float bvv = bias[cnb + l16];
#pragma unroll
            for (int i = 0; i < 4; i++) {
                int cm = m0 + wm + i * 16 + quad * 4;
                int bb = cm >> 10, n = cm & 1023;
                ushort4 o;
                o.x = f2bf(acc[i][j][0] + bvv);
                o.y = f2bf(acc[i][j][1] + bvv);
                o.z = f2bf(acc[i][j][2] + bvv);
                o.w = f2bf(acc[i][j][3] + bvv);
                *(ushort4*)&Vp[((size_t)((bb * 12 + h) * 64 + dv)) * 1024 + n] = o;
            }
        }
    } else {
        // swapped: D row = feature f0+r, col = token.
#pragma unroll
        for (int j = 0; j < 4; j++) {
            int f0 = n0 + wn + j * 16 + quad * 4;
            float4 bv4 = *(const float4*)&bias[f0];
            int qk = f0 >= 768;
            int hd = f0 - qk * 768;
            int h  = hd >> 6;
            int d0 = hd & 63;
            u16* dst = qk ? Kp : Qp;
#pragma unroll
            for (int i = 0; i < 4; i++) {
                int t = m0 + wm + i * 16 + l16;
                int bb = t >> 10, n = t & 1023;
                ushort4 o;
                o.x = f2bf(acc[i][j][0] + bv4.x);
                o.y = f2bf(acc[i][j][1] + bv4.y);
                o.z = f2bf(acc[i][j][2] + bv4.z);
                o.w = f2bf(acc[i][j][3] + bv4.w);
                *(ushort4*)&dst[((size_t)((bb * 12 + h) * 1024 + n)) * 64 + d0] = o;
            }
        }
    }
}

// ---------------------------------------------------------------------------
// Out-projection GEMM (fp32 out, SWAPPED), 2-phase double-buffered staging.
// (R7 version, known-good.)
// ---------------------------------------------------------------------------
__global__ __launch_bounds__(256)
void gemm_out_kernel(const u16* __restrict__ A, const u16* __restrict__ Bt,
                     const float* __restrict__ bias, float* __restrict__ Cout,
                     int M, int N, int K) {
    __shared__ __attribute__((aligned(16))) u16 As[2][128 * 64];
    __shared__ __attribute__((aligned(16))) u16 Bs[2][128 * 64];

    const int tid  = threadIdx.x;
    const int lane = tid & 63;
    const int wave = tid >> 6;
    const int l16  = lane & 15;
    const int quad = lane >> 4;
    const int nxt = N >> 7;
    const int cpx = (int)gridDim.x >> 3;
    const int swz = ((int)blockIdx.x & 7) * cpx + ((int)blockIdx.x >> 3);
    const int m0 = (swz / nxt) * 128;
    const int n0 = (swz % nxt) * 128;
    const int wm = (wave & 1) * 64;
    const int wn = (wave >> 1) * 64;

    f32x4 acc[4][4];
#pragma unroll
    for (int i = 0; i < 4; i++)
#pragma unroll
        for (int j = 0; j < 4; j++) acc[i][j] = (f32x4){0.f, 0.f, 0.f, 0.f};

    const int rs   = lane >> 3;
    const int gseg = (lane & 7) ^ rs;
    const u16* Ag[4]; const u16* Bg[4];
#pragma unroll
    for (int c = 0; c < 4; c++) {
        Ag[c] = A  + (size_t)(m0 + c * 32 + wave * 8 + rs) * K + gseg * 8;
        Bg[c] = Bt + (size_t)(n0 + c * 32 + wave * 8 + rs) * K + gseg * 8;
    }
    const int sw7 = l16 & 7;
    const int nk = K >> 6;

    // prologue: stage K-step 0 into buffer 0
#pragma unroll
    for (int c = 0; c < 4; c++) {
        gload_lds16(Ag[c], &As[0][wave * 512 + c * 2048]);
        gload_lds16(Bg[c], &Bs[0][wave * 512 + c * 2048]);
    }

    int cur = 0;
    for (int t = 0; t < nk; ++t) {
        __syncthreads();
        if (t < nk - 1) {
#pragma unroll
            for (int c = 0; c < 4; c++) {
                gload_lds16(Ag[c] + (t + 1) * 64, &As[cur ^ 1][wave * 512 + c * 2048]);
                gload_lds16(Bg[c] + (t + 1) * 64, &Bs[cur ^ 1][wave * 512 + c * 2048]);
            }
        }
        const u16* Asc = As[cur];
        const u16* Bsc = Bs[cur];

        bf16x8 af[4][2], bfr[4][2];
#pragma unroll
        for (int i = 0; i < 4; i++) {
#pragma unroll
            for (int hh = 0; hh < 2; hh++) {
                af[i][hh]  = *(const bf16x8*)&Asc[(wm + i * 16 + l16) * 64 +
                                                  (((hh * 4 + quad) ^ sw7) * 8)];
                bfr[i][hh] = *(const bf16x8*)&Bsc[(wn + i * 16 + l16) * 64 +
                                                  (((hh * 4 + quad) ^ sw7) * 8)];
            }
        }
        __builtin_amdgcn_s_setprio(1);
#pragma unroll
        for (int i = 0; i < 4; i++)
#pragma unroll
            for (int j = 0; j < 4; j++)
#pragma unroll
                for (int hh = 0; hh < 2; hh++)
                    acc[i][j] = __builtin_amdgcn_mfma_f32_16x16x32_bf16(bfr[j][hh], af[i][hh], acc[i][j], 0, 0, 0);
        __builtin_amdgcn_s_setprio(0);
        cur ^= 1;
    }

#pragma unroll
    for (int j = 0; j < 4; j++) {
        int f0 = n0 + wn + j * 16 + quad * 4;
        float4 bv = *(const float4*)&bias[f0];
#pragma unroll
        for (int i = 0; i < 4; i++) {
            int t = m0 + wm + i * 16 + l16;
            float4 o;
            o.x = acc[i][j][0] + bv.x;
            o.y = acc[i][j][1] + bv.y;
            o.z = acc[i][j][2] + bv.z;
            o.w = acc[i][j][3] + bv.w;
            *(float4*)&Cout[(size_t)t * N + f0] = o;
        }
    }
}

// ---------------------------------------------------------------------------
// MFMA flash attention v6b (frozen): 512-thread blocks, grid 768
// (XCD-chunked). Wave owns 32 q-rows. Dbuf K/V staging, setprio on MFMA.
// ---------------------------------------------------------------------------
__global__ __launch_bounds__(512)
void attention_mfma_kernel(const u16* __restrict__ Qp, const u16* __restrict__ Kp,
                           const u16* __restrict__ Vp, u16* __restrict__ attout) {
    __shared__ __attribute__((aligned(16))) u16 Ks[2][64 * 64];   // [key][d], swizzled
    __shared__ __attribute__((aligned(16))) u16 Vs[2][64 * 64];   // [dv][key], swizzled

    const int tid  = threadIdx.x;
    const int wave = tid >> 6;          // 0..7
    const int lane = tid & 63;
    const int l16  = lane & 15;
    const int quad = lane >> 4;
    const int flat = blockIdx.x;
    const int swz  = (flat & 7) * 96 + (flat >> 3);
    const int bh   = swz >> 2;          // 0..191 == head
    const int b    = bh / 12, h = bh % 12;
    const int q0   = (swz & 3) * 256 + wave * 32;

    const u16* Qhead = Qp + (size_t)bh * 1024 * 64;
    const u16* Khead = Kp + (size_t)bh * 1024 * 64;
    const u16* Vhead = Vp + (size_t)bh * 64 * 1024;

    bf16x8 qf[2][2];
#pragma unroll
    for (int qb = 0; qb < 2; qb++) {
        const u16* qrow = Qhead + (size_t)(q0 + qb * 16 + l16) * 64;
        qf[qb][0] = *(const bf16x8*)(qrow + quad * 8);
        qf[qb][1] = *(const bf16x8*)(qrow + 32 + quad * 8);
    }

    f32x4 oacc[2][4];
#pragma unroll
    for (int qb = 0; qb < 2; qb++)
#pragma unroll
        for (int db = 0; db < 4; db++) oacc[qb][db] = (f32x4){0.f, 0.f, 0.f, 0.f};
    float l_part[2] = {0.f, 0.f};

    const int srow = tid >> 3;                  // 0..63
    const int gseg = (tid & 7) ^ (srow & 7);
    const u16* Kg = Khead + (size_t)srow * 64 + gseg * 8;    // + t*4096 per tile
    const u16* Vg = Vhead + (size_t)srow * 1024 + gseg * 8;  // + t*64 per tile
    const int sw7 = l16 & 7;

    gload_lds16(Kg, &Ks[0][wave * 512]);
    gload_lds16(Vg, &Vs[0][wave * 512]);

    int cur = 0;
    for (int t = 0; t < 16; ++t) {
        __syncthreads();
        if (t < 15) {
            gload_lds16(Kg + (t + 1) * 4096, &Ks[cur ^ 1][wave * 512]);
            gload_lds16(Vg + (t + 1) * 64,   &Vs[cur ^ 1][wave * 512]);
        }
        const u16* Ksc = Ks[cur];
        const u16* Vsc = Vs[cur];

        union { uint32_t u[4]; bf16x8 v; } pf8[2][2];   // [qb][jp]
        {
            bf16x8 kf[4][2];
#pragma unroll
            for (int jb = 0; jb < 4; jb++) {
#pragma unroll
                for (int hf = 0; hf < 2; hf++)
                    kf[jb][hf] = *(const bf16x8*)&Ksc[(jb * 16 + l16) * 64 +
                                                      (((hf * 4 + quad) ^ sw7) * 8)];
            }
#pragma unroll
            for (int qb = 0; qb < 2; qb++) {
#pragma unroll
                for (int jb = 0; jb < 4; jb++) {
                    f32x4 st = (f32x4){0.f, 0.f, 0.f, 0.f};
                    __builtin_amdgcn_s_setprio(1);
                    st = __builtin_amdgcn_mfma_f32_16x16x32_bf16(kf[jb][0], qf[qb][0], st, 0, 0, 0);
                    st = __builtin_amdgcn_mfma_f32_16x16x32_bf16(kf[jb][1], qf[qb][1], st, 0, 0, 0);
                    __builtin_amdgcn_s_setprio(0);
                    float e0 = __expf(st[0]), e1 = __expf(st[1]);
                    float e2 = __expf(st[2]), e3 = __expf(st[3]);
                    l_part[qb] += (e0 + e1) + (e2 + e3);
                    union { __hip_bfloat162 h2; uint32_t u; } c0, c1;
                    c0.h2 = __float22bfloat162_rn(make_float2(e0, e1));
                    c1.h2 = __float22bfloat162_rn(make_float2(e2, e3));
                    pf8[qb][jb >> 1].u[(jb & 1) * 2 + 0] = c0.u;
                    pf8[qb][jb >> 1].u[(jb & 1) * 2 + 1] = c1.u;
                }
            }
        }

        __builtin_amdgcn_s_setprio(1);
#pragma unroll
        for (int db = 0; db < 4; db++) {
#pragma unroll
            for (int jp = 0; jp < 2; jp++) {
                union { s16x4 hh[2]; bf16x8 v; } vb8;
                int glo = 4 * jp + (quad >> 1);
                int ghi = glo + 2;
                vb8.hh[0] = *(const s16x4*)&Vsc[(db * 16 + l16) * 64 +
                                                ((glo ^ sw7) * 8) + (quad & 1) * 4];
                vb8.hh[1] = *(const s16x4*)&Vsc[(db * 16 + l16) * 64 +
                                                ((ghi ^ sw7) * 8) + (quad & 1) * 4];
#pragma unroll
                for (int qb = 0; qb < 2; qb++)
                    oacc[qb][db] = __builtin_amdgcn_mfma_f32_16x16x32_bf16(
                        pf8[qb][jp].v, vb8.v, oacc[qb][db], 0, 0, 0);
            }
        }
        __builtin_amdgcn_s_setprio(0);
        cur ^= 1;
    }

#pragma unroll
    for (int qb = 0; qb < 2; qb++) {
        float l = l_part[qb];
        l += __shfl_xor(l, 16);
        l += __shfl_xor(l, 32);
        float linv[4];
#pragma unroll
        for (int r = 0; r < 4; r++)
            linv[r] = 1.0f / __shfl(l, quad * 4 + r);
        u16* orow = attout + (size_t)(b * 1024 + q0 + qb * 16 + quad * 4) * 768 + h * 64 + l16;
#pragma unroll
        for (int db = 0; db < 4; db++)
#pragma unroll
            for (int r = 0; r < 4; r++)
                orow[(size_t)r * 768 + db * 16] = f2bf(oacc[qb][db][r] * linv[r]);
    }
}

// ---------------------------------------------------------------------------
extern "C" void kernel_launch(void* const* d_in, const int* in_sizes, int n_in,
                              void* d_out, int out_size, void* d_ws, size_t ws_size,
                              hipStream_t stream) {
    const float* x      = (const float*)d_in[0];
    const float* W_qk   = (const float*)d_in[1];
    const float* b_qk   = (const float*)d_in[2];
    const float* W_v    = (const float*)d_in[3];
    const float* b_v    = (const float*)d_in[4];
    const float* W_proj = (const float*)d_in[5];
    const float* b_proj = (const float*)d_in[6];
    float* out = (float*)d_out;

    char* ws = (char*)d_ws;
    size_t off = 0;
    auto alloc = [&](size_t bytes) { void* p = ws + off; off += (bytes + 255) & ~255ull; return p; };
    u16*   xb     = (u16*)alloc((size_t)16384 * 768 * 2);
    u16*   Wqkt   = (u16*)alloc((size_t)1536 * 768 * 2);
    float* bqkp   = (float*)alloc(1536 * 4);
    u16*   Wvt    = (u16*)alloc((size_t)768 * 768 * 2);
    u16*   Wprojt = (u16*)alloc((size_t)768 * 768 * 2);
    u16*   Qp     = (u16*)alloc((size_t)16384 * 768 * 2);
    u16*   Kp     = (u16*)alloc((size_t)16384 * 768 * 2);
    u16*   Vp     = (u16*)alloc((size_t)16384 * 768 * 2);
    u16*   attout = (u16*)alloc((size_t)16384 * 768 * 2);

    // merged prep: convert + both weight transposes in one dispatch
    prep_kernel<<<14592, 256, 0, stream>>>(x, xb, W_qk, b_qk, Wqkt, bqkp,
                                           W_v, Wvt, W_proj, Wprojt);

    // fused QK+V projection (Q pre-scaled by 0.125)
    gemm_qkv_kernel<<<2304, 256, 0, stream>>>(xb, Wqkt, Wvt, bqkp, b_v, Qp, Kp, Vp);
    // attention -> attout (bf16, [token][768])
    attention_mfma_kernel<<<768, 512, 0, stream>>>(Qp, Kp, Vp, attout);
    // output projection -> d_out (fp32)
    gemm_out_kernel<<<768, 256, 0, stream>>>(attout, Wprojt, b_proj, out, 16384, 768, 768);
}